// Round 5
// baseline (104.988 us; speedup 1.0000x reference)
//
#include <hip/hip_runtime.h>
#include <stdint.h>

#define BTOT 4096
#define DD   256
#define SS   32
#define KKN  32
#define NGEMM 528          // 32*33/2 triangular tiles
#define NBLK  (BTOT + NGEMM)

typedef unsigned short u16;
using f32x4  = __attribute__((ext_vector_type(4))) float;
using bf16x8 = __attribute__((ext_vector_type(8))) short;

__device__ __forceinline__ u16 f2bf(float f) {
    uint32_t u = __builtin_bit_cast(uint32_t, f);
    u = (u + 0x7FFFu + ((u >> 16) & 1u)) >> 16;
    return (u16)u;
}
__device__ __forceinline__ float bf2f(u16 h) {
    uint32_t u = ((uint32_t)h) << 16;
    return __builtin_bit_cast(float, u);
}

// ---- kernel 0: cast embeddings fp32 -> bf16 ----
__global__ __launch_bounds__(256) void cast_kernel(const float* __restrict__ E,
                                                   u16* __restrict__ ebf) {
    int idx = blockIdx.x * 256 + threadIdx.x;
    const float4* p = reinterpret_cast<const float4*>(E) + (size_t)idx * 2;
    float4 a = p[0], b = p[1];
    uint4 o;
    o.x = (uint32_t)f2bf(a.x) | ((uint32_t)f2bf(a.y) << 16);
    o.y = (uint32_t)f2bf(a.z) | ((uint32_t)f2bf(a.w) << 16);
    o.z = (uint32_t)f2bf(b.x) | ((uint32_t)f2bf(b.y) << 16);
    o.w = (uint32_t)f2bf(b.z) | ((uint32_t)f2bf(b.w) << 16);
    reinterpret_cast<uint4*>(ebf)[idx] = o;
}

// ---- fat kernel: 1-in-8 blocks = triangular GEMM tile, rest = simdiv row ----
// GEMM rides for free under the HBM-streaming simdiv waves (MFMA and VMEM
// pipes overlap across waves). LDS = 64KB dynamic caps residency at 2
// blocks/CU, so the GEMM path's 136-reg weight does not cost occupancy.
__global__ __launch_bounds__(256) void fat_kernel(
    const float* __restrict__ E, const float* __restrict__ Sim, const float* __restrict__ Div,
    const u16* __restrict__ ebf, const int* __restrict__ labels,
    float* __restrict__ gden, float* __restrict__ gnum,
    float* __restrict__ sdden, float* __restrict__ sdnum)
{
    extern __shared__ char dyn[];
    int bid  = blockIdx.x;
    int t    = threadIdx.x;
    int w    = t >> 6;
    int lane = t & 63;

    bool is_gemm = (bid < NGEMM * 8) && ((bid & 7) == 7);

    if (is_gemm) {
        // ================= GEMM path (triangular, unique-writer) =================
        u16*   As   = (u16*)dyn;                       // 8 KB
        u16*   Bs   = (u16*)(dyn + 8192);              // 8 KB
        float* rbuf = (float*)(dyn + 16384);           // [2][2][128] = 2 KB
        float* cbuf = (float*)(dyn + 16384 + 2048);    // [2][2][128] = 2 KB

        int g = bid >> 3;
        int R = (int)((65.0f - sqrtf(4225.0f - 8.0f * (float)g)) * 0.5f);
        while (R > 0 && R * (65 - R) / 2 > g) --R;
        while ((R + 1) * (64 - R) / 2 <= g) ++R;
        int C = R + (g - R * (65 - R) / 2);

        int brow = R * 128, bcol = C * 128;
        int wr = w >> 1, wc = w & 1;
        int r16 = lane & 15, hi = lane >> 4;
        int kq = hi * 8;

        f32x4 acc[4][4] = {};

        for (int kt = 0; kt < DD / 32; ++kt) {
            int k0 = kt * 32;
            #pragma unroll
            for (int it = 0; it < 2; ++it) {
                int c   = t + 256 * it;
                int row = c >> 2;
                int col = (c & 3) * 8;
                const u16* ga = &ebf[(size_t)(brow + row) * DD + k0 + col];
                const u16* gb = &ebf[(size_t)(bcol + row) * DD + k0 + col];
                __builtin_amdgcn_global_load_lds(
                    (const __attribute__((address_space(1))) unsigned int*)ga,
                    (__attribute__((address_space(3))) unsigned int*)&As[c * 8], 16, 0, 0);
                __builtin_amdgcn_global_load_lds(
                    (const __attribute__((address_space(1))) unsigned int*)gb,
                    (__attribute__((address_space(3))) unsigned int*)&Bs[c * 8], 16, 0, 0);
            }
            __syncthreads();

            bf16x8 af[4], bfr[4];
            #pragma unroll
            for (int m = 0; m < 4; ++m)
                af[m] = *(const bf16x8*)&As[(wr * 64 + m * 16 + r16) * 32 + kq];
            #pragma unroll
            for (int n = 0; n < 4; ++n)
                bfr[n] = *(const bf16x8*)&Bs[(wc * 64 + n * 16 + r16) * 32 + kq];
            #pragma unroll
            for (int m = 0; m < 4; ++m)
                #pragma unroll
                for (int n = 0; n < 4; ++n)
                    acc[m][n] = __builtin_amdgcn_mfma_f32_16x16x32_bf16(af[m], bfr[n], acc[m][n], 0, 0, 0);
            __syncthreads();
        }

        bool offdiag = (C != R);

        float malf[4];
        #pragma unroll
        for (int n = 0; n < 4; ++n)
            malf[n] = (float)labels[bcol + wc * 64 + n * 16 + r16];
        float malr[16];
        #pragma unroll
        for (int m = 0; m < 4; ++m)
            #pragma unroll
            for (int r = 0; r < 4; ++r)
                malr[m * 4 + r] = (float)labels[brow + wr * 64 + m * 16 + hi * 4 + r];

        float cd[4] = {0.f, 0.f, 0.f, 0.f}, cn[4] = {0.f, 0.f, 0.f, 0.f};

        // row partials (wave's 64 rows x its 64-col strip) -> rbuf[.][wc][.]
        #pragma unroll
        for (int m = 0; m < 4; ++m) {
            #pragma unroll
            for (int r = 0; r < 4; ++r) {
                float pe = 0.f, pn = 0.f;
                #pragma unroll
                for (int n = 0; n < 4; ++n) {
                    float v  = acc[m][n][r];
                    float ex = __expf(v);
                    pe += ex;
                    pn += malf[n] * v;
                    cd[n] += ex;
                    cn[n] += malr[m * 4 + r] * v;
                }
                #pragma unroll
                for (int s = 1; s < 16; s <<= 1) {
                    pe += __shfl_xor(pe, s, 64);
                    pn += __shfl_xor(pn, s, 64);
                }
                if (r16 == 0) {
                    int rl = wr * 64 + m * 16 + hi * 4 + r;
                    rbuf[0 * 256 + wc * 128 + rl] = pe;
                    rbuf[1 * 256 + wc * 128 + rl] = pn;
                }
            }
        }

        // col partials (wave's 64 cols x its 64-row strip) -> cbuf[.][wr][.]
        if (offdiag) {
            #pragma unroll
            for (int n = 0; n < 4; ++n) {
                cd[n] += __shfl_xor(cd[n], 16, 64);
                cd[n] += __shfl_xor(cd[n], 32, 64);
                cn[n] += __shfl_xor(cn[n], 16, 64);
                cn[n] += __shfl_xor(cn[n], 32, 64);
                if (lane < 16) {
                    int cl = wc * 64 + n * 16 + lane;
                    cbuf[0 * 256 + wr * 128 + cl] = cd[n];
                    cbuf[1 * 256 + wr * 128 + cl] = cn[n];
                }
            }
        }
        __syncthreads();

        if (t < 128) {
            int i = brow + t;
            gden[(size_t)i * 32 + C] = rbuf[0 * 256 + 0 + t] + rbuf[0 * 256 + 128 + t];
            gnum[(size_t)i * 32 + C] = rbuf[1 * 256 + 0 + t] + rbuf[1 * 256 + 128 + t];
        } else if (offdiag) {
            int tt = t - 128;
            int j = bcol + tt;
            gden[(size_t)j * 32 + R] = cbuf[0 * 256 + 0 + tt] + cbuf[0 * 256 + 128 + tt];
            gnum[(size_t)j * 32 + R] = cbuf[1 * 256 + 0 + tt] + cbuf[1 * 256 + 128 + tt];
        }
    } else {
        // ================= simdiv path (bulk LDS staging, counted vmcnt) =================
        float* lds  = (float*)dyn;                    // 64 * 256 floats = 64 KB
        float* sbuf = (float*)(dyn + 64 * 1024);      // 8 floats combine buffer

        int i = (bid < NGEMM * 8) ? bid - (bid >> 3) : bid - NGEMM;
        int g = lane >> 4, sub = lane & 15;

        // E row first: exactly 4 vmem instrs per wave, counted in the vmcnt math
        const float4* E4 = reinterpret_cast<const float4*>(E + (size_t)i * DD);
        float4 e0 = E4[0 * 16 + sub], e1 = E4[1 * 16 + sub];
        float4 e2 = E4[2 * 16 + sub], e3 = E4[3 * 16 + sub];
        asm volatile("" ::: "memory");   // pin E loads before the stage queue

        // stage: wave w owns vectors v = w*16 + vt (fire-and-forget, 16 KB in flight)
        #pragma unroll
        for (int vt = 0; vt < 16; ++vt) {
            int v = w * 16 + vt;
            const float* src = (v < SS) ? (Sim + ((size_t)i * SS + v) * DD)
                                        : (Div + ((size_t)i * KKN + (v - SS)) * DD);
            __builtin_amdgcn_global_load_lds(
                (const __attribute__((address_space(1))) unsigned int*)(src + lane * 4),
                (__attribute__((address_space(3))) unsigned int*)(lds + (size_t)v * DD), 16, 0, 0);
        }

        float accs = 0.f, acce = 0.f;

#define SD_STEP(VT, CNT)                                                          \
    {                                                                             \
        asm volatile("s_waitcnt vmcnt(" #CNT ")" ::: "memory");                   \
        int v = w * 16 + (VT) * 4 + g;                                            \
        const float4* row = reinterpret_cast<const float4*>(lds + (size_t)v * DD);\
        float4 s0 = row[0 * 16 + sub], s1 = row[1 * 16 + sub];                    \
        float4 s2 = row[2 * 16 + sub], s3 = row[3 * 16 + sub];                    \
        float d = e0.x * s0.x + e0.y * s0.y + e0.z * s0.z + e0.w * s0.w           \
                + e1.x * s1.x + e1.y * s1.y + e1.z * s1.z + e1.w * s1.w           \
                + e2.x * s2.x + e2.y * s2.y + e2.z * s2.z + e2.w * s2.w           \
                + e3.x * s3.x + e3.y * s3.y + e3.z * s3.z + e3.w * s3.w;          \
        d += __shfl_xor(d, 1, 64);                                                \
        d += __shfl_xor(d, 2, 64);                                                \
        d += __shfl_xor(d, 4, 64);                                                \
        d += __shfl_xor(d, 8, 64);                                                \
        accs += d;                                                                \
        acce += __expf(d);                                                        \
    }

        SD_STEP(0, 12)
        SD_STEP(1, 8)
        SD_STEP(2, 4)
        SD_STEP(3, 0)
#undef SD_STEP

        accs += __shfl_xor(accs, 16, 64);
        accs += __shfl_xor(accs, 32, 64);
        acce += __shfl_xor(acce, 16, 64);
        acce += __shfl_xor(acce, 32, 64);

        // self-term: bf16-rounded ||e||^2 (matches MFMA diagonal), wave 0 only
        float sd = 0.f;
        if (w == 0) {
            float c;
            c = bf2f(f2bf(e0.x)); sd += c * c;  c = bf2f(f2bf(e0.y)); sd += c * c;
            c = bf2f(f2bf(e0.z)); sd += c * c;  c = bf2f(f2bf(e0.w)); sd += c * c;
            c = bf2f(f2bf(e1.x)); sd += c * c;  c = bf2f(f2bf(e1.y)); sd += c * c;
            c = bf2f(f2bf(e1.z)); sd += c * c;  c = bf2f(f2bf(e1.w)); sd += c * c;
            c = bf2f(f2bf(e2.x)); sd += c * c;  c = bf2f(f2bf(e2.y)); sd += c * c;
            c = bf2f(f2bf(e2.z)); sd += c * c;  c = bf2f(f2bf(e2.w)); sd += c * c;
            c = bf2f(f2bf(e3.x)); sd += c * c;  c = bf2f(f2bf(e3.y)); sd += c * c;
            c = bf2f(f2bf(e3.z)); sd += c * c;  c = bf2f(f2bf(e3.w)); sd += c * c;
            sd += __shfl_xor(sd, 1, 64);
            sd += __shfl_xor(sd, 2, 64);
            sd += __shfl_xor(sd, 4, 64);
            sd += __shfl_xor(sd, 8, 64);
        }

        __syncthreads();   // all staging LDS consumed; safe to reuse for combine
        if (lane == 0) {
            float addn = accs, addd = acce;
            if (w == 0) {
                addd -= __expf(sd);
                addn -= (float)labels[i] * sd;
            }
            sbuf[w * 2]     = addn;
            sbuf[w * 2 + 1] = addd;
        }
        __syncthreads();
        if (t == 0) {
            sdnum[i] = sbuf[0] + sbuf[2] + sbuf[4] + sbuf[6];
            sdden[i] = sbuf[1] + sbuf[3] + sbuf[5] + sbuf[7];
        }
    }
}

// ---- kernel 3: per-row fold (33 partials) + per-block loss partials ----
__global__ __launch_bounds__(128) void reduce1_kernel(
    const int* __restrict__ labels, const float* __restrict__ gden,
    const float* __restrict__ gnum, const float* __restrict__ sdden,
    const float* __restrict__ sdnum, float* __restrict__ part)
{
    __shared__ float sA[128], sB[128];
    __shared__ int   sC[128];
    int p = blockIdx.x, t = threadIdx.x;
    int i = p * 128 + t;

    const float4* dr = reinterpret_cast<const float4*>(gden + (size_t)i * 32);
    const float4* nr = reinterpret_cast<const float4*>(gnum + (size_t)i * 32);
    float den = sdden[i], num = sdnum[i];
    #pragma unroll
    for (int c = 0; c < 8; ++c) {
        float4 a = dr[c]; den += a.x + a.y + a.z + a.w;
        float4 b = nr[c]; num += b.x + b.y + b.z + b.w;
    }
    int lab = labels[i];
    sA[t] = lab ? __logf(den) : 0.f;
    sB[t] = lab ? num : 0.f;
    sC[t] = lab;
    __syncthreads();
    for (int s = 64; s > 0; s >>= 1) {
        if (t < s) { sA[t] += sA[t + s]; sB[t] += sB[t + s]; sC[t] += sC[t + s]; }
        __syncthreads();
    }
    if (t == 0) {
        part[p]      = sA[0];
        part[32 + p] = sB[0];
        part[64 + p] = (float)sC[0];
    }
}

// ---- kernel 4: final scalar combine ----
__global__ __launch_bounds__(64) void final_kernel(const float* __restrict__ part,
                                                   float* __restrict__ out)
{
    int lane = threadIdx.x;
    float lg = (lane < 32) ? part[lane]      : 0.f;
    float nm = (lane < 32) ? part[32 + lane] : 0.f;
    float ml = (lane < 32) ? part[64 + lane] : 0.f;
    #pragma unroll
    for (int s = 1; s < 64; s <<= 1) {
        lg += __shfl_xor(lg, s, 64);
        nm += __shfl_xor(nm, s, 64);
        ml += __shfl_xor(ml, s, 64);
    }
    if (lane == 0) {
        float cnt = ml - 1.f + (float)(SS + KKN);
        out[0] = (lg - nm / cnt) / (float)BTOT;
    }
}

extern "C" void kernel_launch(void* const* d_in, const int* in_sizes, int n_in,
                              void* d_out, int out_size, void* d_ws, size_t ws_size,
                              hipStream_t stream) {
    const float* E   = (const float*)d_in[0];
    const float* Sim = (const float*)d_in[1];
    const float* Div = (const float*)d_in[2];
    const int* labels = (const int*)d_in[3];
    float* out = (float*)d_out;

    char* ws = (char*)d_ws;
    u16*   ebf   = (u16*)ws;   ws += (size_t)BTOT * DD * sizeof(u16);
    float* gden  = (float*)ws; ws += (size_t)BTOT * 32 * sizeof(float);
    float* gnum  = (float*)ws; ws += (size_t)BTOT * 32 * sizeof(float);
    float* sdden = (float*)ws; ws += BTOT * sizeof(float);
    float* sdnum = (float*)ws; ws += BTOT * sizeof(float);
    float* part  = (float*)ws;

    cast_kernel<<<BTOT * DD / 8 / 256, 256, 0, stream>>>(E, ebf);
    fat_kernel<<<NBLK, 256, 64 * 1024 + 64, stream>>>(E, Sim, Div, ebf, labels,
                                                      gden, gnum, sdden, sdnum);
    reduce1_kernel<<<32, 128, 0, stream>>>(labels, gden, gnum, sdden, sdnum, part);
    final_kernel<<<1, 64, 0, stream>>>(part, out);
}

// Round 6
// 77.688 us; speedup vs baseline: 1.3514x; 1.3514x over previous
//
#include <hip/hip_runtime.h>
#include <stdint.h>

#define BTOT 4096
#define DD   256
#define SS   32
#define KKN  32
#define NGEMM 528          // 32*33/2 triangular tiles
#define NROWB 8            // rows per simdiv block
#define SDBLK (BTOT / NROWB)   // 512 persistent simdiv blocks

typedef unsigned short u16;
using f32x4  = __attribute__((ext_vector_type(4))) float;
using bf16x8 = __attribute__((ext_vector_type(8))) short;

__device__ __forceinline__ u16 f2bf(float f) {
    uint32_t u = __builtin_bit_cast(uint32_t, f);
    u = (u + 0x7FFFu + ((u >> 16) & 1u)) >> 16;
    return (u16)u;
}
__device__ __forceinline__ float bf2f(u16 h) {
    uint32_t u = ((uint32_t)h) << 16;
    return __builtin_bit_cast(float, u);
}

// ---- kernel 0: cast embeddings fp32 -> bf16 ----
__global__ __launch_bounds__(256) void cast_kernel(const float* __restrict__ E,
                                                   u16* __restrict__ ebf) {
    int idx = blockIdx.x * 256 + threadIdx.x;
    const float4* p = reinterpret_cast<const float4*>(E) + (size_t)idx * 2;
    float4 a = p[0], b = p[1];
    uint4 o;
    o.x = (uint32_t)f2bf(a.x) | ((uint32_t)f2bf(a.y) << 16);
    o.y = (uint32_t)f2bf(a.z) | ((uint32_t)f2bf(a.w) << 16);
    o.z = (uint32_t)f2bf(b.x) | ((uint32_t)f2bf(b.y) << 16);
    o.w = (uint32_t)f2bf(b.z) | ((uint32_t)f2bf(b.w) << 16);
    reinterpret_cast<uint4*>(ebf)[idx] = o;
}

// ---- kernel 1: symmetric E@E^T, upper-triangular tiles (round-4, unchanged) ----
__global__ __launch_bounds__(256) void gemm_kernel(
    const u16* __restrict__ ebf, const int* __restrict__ labels,
    float* __restrict__ gden, float* __restrict__ gnum)
{
    __shared__ u16 As[128 * 32];
    __shared__ u16 Bs[128 * 32];
    __shared__ float rbuf[2][2][128];
    __shared__ float cbuf[2][2][128];

    int bid = blockIdx.x;
    int R = (int)((65.0f - sqrtf(4225.0f - 8.0f * (float)bid)) * 0.5f);
    while (R > 0 && R * (65 - R) / 2 > bid) --R;
    while ((R + 1) * (64 - R) / 2 <= bid) ++R;
    int C = R + (bid - R * (65 - R) / 2);

    int brow = R * 128, bcol = C * 128;
    int t = threadIdx.x, w = t >> 6, lane = t & 63;
    int wr = w >> 1, wc = w & 1;
    int r16 = lane & 15, hi = lane >> 4;
    int kq = hi * 8;

    f32x4 acc[4][4] = {};

    for (int kt = 0; kt < DD / 32; ++kt) {
        int k0 = kt * 32;
        #pragma unroll
        for (int it = 0; it < 2; ++it) {
            int c   = t + 256 * it;
            int row = c >> 2;
            int col = (c & 3) * 8;
            const u16* ga = &ebf[(size_t)(brow + row) * DD + k0 + col];
            const u16* gb = &ebf[(size_t)(bcol + row) * DD + k0 + col];
            __builtin_amdgcn_global_load_lds(
                (const __attribute__((address_space(1))) unsigned int*)ga,
                (__attribute__((address_space(3))) unsigned int*)&As[c * 8], 16, 0, 0);
            __builtin_amdgcn_global_load_lds(
                (const __attribute__((address_space(1))) unsigned int*)gb,
                (__attribute__((address_space(3))) unsigned int*)&Bs[c * 8], 16, 0, 0);
        }
        __syncthreads();

        bf16x8 af[4], bfr[4];
        #pragma unroll
        for (int m = 0; m < 4; ++m)
            af[m] = *(const bf16x8*)&As[(wr * 64 + m * 16 + r16) * 32 + kq];
        #pragma unroll
        for (int n = 0; n < 4; ++n)
            bfr[n] = *(const bf16x8*)&Bs[(wc * 64 + n * 16 + r16) * 32 + kq];
        #pragma unroll
        for (int m = 0; m < 4; ++m)
            #pragma unroll
            for (int n = 0; n < 4; ++n)
                acc[m][n] = __builtin_amdgcn_mfma_f32_16x16x32_bf16(af[m], bfr[n], acc[m][n], 0, 0, 0);
        __syncthreads();
    }

    bool offdiag = (C != R);

    float malf[4];
    #pragma unroll
    for (int n = 0; n < 4; ++n)
        malf[n] = (float)labels[bcol + wc * 64 + n * 16 + r16];
    float malr[16];
    #pragma unroll
    for (int m = 0; m < 4; ++m)
        #pragma unroll
        for (int r = 0; r < 4; ++r)
            malr[m * 4 + r] = (float)labels[brow + wr * 64 + m * 16 + hi * 4 + r];

    float cd[4] = {0.f, 0.f, 0.f, 0.f}, cn[4] = {0.f, 0.f, 0.f, 0.f};

    #pragma unroll
    for (int m = 0; m < 4; ++m) {
        #pragma unroll
        for (int r = 0; r < 4; ++r) {
            float pe = 0.f, pn = 0.f;
            #pragma unroll
            for (int n = 0; n < 4; ++n) {
                float v  = acc[m][n][r];
                float ex = __expf(v);
                pe += ex;
                pn += malf[n] * v;
                cd[n] += ex;
                cn[n] += malr[m * 4 + r] * v;
            }
            #pragma unroll
            for (int s = 1; s < 16; s <<= 1) {
                pe += __shfl_xor(pe, s, 64);
                pn += __shfl_xor(pn, s, 64);
            }
            if (r16 == 0) {
                int rl = wr * 64 + m * 16 + hi * 4 + r;
                rbuf[0][wc][rl] = pe;
                rbuf[1][wc][rl] = pn;
            }
        }
    }

    if (offdiag) {
        #pragma unroll
        for (int n = 0; n < 4; ++n) {
            cd[n] += __shfl_xor(cd[n], 16, 64);
            cd[n] += __shfl_xor(cd[n], 32, 64);
            cn[n] += __shfl_xor(cn[n], 16, 64);
            cn[n] += __shfl_xor(cn[n], 32, 64);
            if (lane < 16) {
                int cl = wc * 64 + n * 16 + lane;
                cbuf[0][wr][cl] = cd[n];
                cbuf[1][wr][cl] = cn[n];
            }
        }
    }
    __syncthreads();

    if (t < 128) {
        int i = brow + t;
        gden[(size_t)i * 32 + C] = rbuf[0][0][t] + rbuf[0][1][t];
        gnum[(size_t)i * 32 + C] = rbuf[1][0][t] + rbuf[1][1][t];
    } else if (offdiag) {
        int tt = t - 128;
        int j = bcol + tt;
        gden[(size_t)j * 32 + R] = cbuf[0][0][tt] + cbuf[0][1][tt];
        gnum[(size_t)j * 32 + R] = cbuf[1][0][tt] + cbuf[1][1][tt];
    }
}

// ---- kernel 2: persistent, software-pipelined simdiv ----
// 512 blocks x 8 rows. Per wave: rolling vmcnt queue of 17 LDS-DMA ops
// (1 E-row + 16 vectors); steady-state waits vmcnt(12/13/13/13) never
// drain the queue until the final row. No barriers/atomics in the loop;
// per-(row,wave) partials + self-dot land in LDS scratch, flushed once.
__global__ __launch_bounds__(256) void simdiv_kernel(
    const float* __restrict__ E, const float* __restrict__ Sim, const float* __restrict__ Div,
    float* __restrict__ sdpart)
{
    extern __shared__ char dyn[];
    float* stg = (float*)dyn;                        // [4 waves][16 vec][256] = 64 KB
    float* eld = (float*)(dyn + 65536);              // [4 waves][2][256]      = 8 KB
    float* scr = (float*)(dyn + 65536 + 8192);       // [8 rows][12]           = 384 B

    int b = blockIdx.x;
    int t = threadIdx.x, w = t >> 6, lane = t & 63;
    int g = lane >> 4, sub = lane & 15;
    int i0 = b * NROWB;

    float* wstg = stg + w * 16 * 256;
    float* weld = eld + w * 2 * 256;

#define STAGE_E(I, P)                                                                        \
    __builtin_amdgcn_global_load_lds(                                                        \
        (const __attribute__((address_space(1))) unsigned int*)(E + (size_t)(I) * DD + lane * 4), \
        (__attribute__((address_space(3))) unsigned int*)(weld + (P) * 256), 16, 0, 0)

#define STAGE_V(I, Q)                                                                        \
    {                                                                                        \
        int v_ = w * 16 + (Q);                                                               \
        const float* s_ = (v_ < SS) ? (Sim + ((size_t)(I) * SS + v_) * DD)                   \
                                    : (Div + ((size_t)(I) * KKN + (v_ - SS)) * DD);          \
        __builtin_amdgcn_global_load_lds(                                                    \
            (const __attribute__((address_space(1))) unsigned int*)(s_ + lane * 4),          \
            (__attribute__((address_space(3))) unsigned int*)(wstg + (Q) * 256), 16, 0, 0);  \
    }

#define COMP(CC)                                                                             \
    {                                                                                        \
        const float4* row_ = (const float4*)(wstg + ((CC) * 4 + g) * 256);                   \
        float4 s0 = row_[0 * 16 + sub], s1 = row_[1 * 16 + sub];                             \
        float4 s2 = row_[2 * 16 + sub], s3 = row_[3 * 16 + sub];                             \
        float d = e0.x * s0.x + e0.y * s0.y + e0.z * s0.z + e0.w * s0.w                      \
                + e1.x * s1.x + e1.y * s1.y + e1.z * s1.z + e1.w * s1.w                      \
                + e2.x * s2.x + e2.y * s2.y + e2.z * s2.z + e2.w * s2.w                      \
                + e3.x * s3.x + e3.y * s3.y + e3.z * s3.z + e3.w * s3.w;                     \
        d += __shfl_xor(d, 1, 64);                                                           \
        d += __shfl_xor(d, 2, 64);                                                           \
        d += __shfl_xor(d, 4, 64);                                                           \
        d += __shfl_xor(d, 8, 64);                                                           \
        accs += d;                                                                           \
        acce += __expf(d);                                                                   \
    }

    // prologue: E(row0) + 4 chunks of row0  (17 ops in flight)
    STAGE_E(i0, 0);
    #pragma unroll
    for (int q = 0; q < 16; ++q) STAGE_V(i0, q);

    #pragma unroll 1
    for (int r = 0; r < NROWB; ++r) {
        int i = i0 + r;
        int p = r & 1;
        bool more = (r < NROWB - 1);

        float accs = 0.f, acce = 0.f;
        float4 e0, e1, e2, e3;

        // step 0: need E(r)+chunk0 (oldest 5 of 17)
        asm volatile("s_waitcnt vmcnt(12)" ::: "memory");
        {
            const float4* ep = (const float4*)(weld + p * 256);
            e0 = ep[0 * 16 + sub]; e1 = ep[1 * 16 + sub];
            e2 = ep[2 * 16 + sub]; e3 = ep[3 * 16 + sub];
        }
        COMP(0)
        if (more) {
            STAGE_E(i + 1, p ^ 1);
            STAGE_V(i + 1, 0) STAGE_V(i + 1, 1) STAGE_V(i + 1, 2) STAGE_V(i + 1, 3)
        }

        // step 1
        if (more) { asm volatile("s_waitcnt vmcnt(13)" ::: "memory"); }
        else      { asm volatile("s_waitcnt vmcnt(8)"  ::: "memory"); }
        COMP(1)
        if (more) { STAGE_V(i + 1, 4) STAGE_V(i + 1, 5) STAGE_V(i + 1, 6) STAGE_V(i + 1, 7) }

        // step 2
        if (more) { asm volatile("s_waitcnt vmcnt(13)" ::: "memory"); }
        else      { asm volatile("s_waitcnt vmcnt(4)"  ::: "memory"); }
        COMP(2)
        if (more) { STAGE_V(i + 1, 8) STAGE_V(i + 1, 9) STAGE_V(i + 1, 10) STAGE_V(i + 1, 11) }

        // step 3
        if (more) { asm volatile("s_waitcnt vmcnt(13)" ::: "memory"); }
        else      { asm volatile("s_waitcnt vmcnt(0)"  ::: "memory"); }
        COMP(3)
        if (more) { STAGE_V(i + 1, 12) STAGE_V(i + 1, 13) STAGE_V(i + 1, 14) STAGE_V(i + 1, 15) }

        // cross-group reduce for this row
        accs += __shfl_xor(accs, 16, 64);
        accs += __shfl_xor(accs, 32, 64);
        acce += __shfl_xor(acce, 16, 64);
        acce += __shfl_xor(acce, 32, 64);

        // self-dot (bf16-rounded, matches MFMA diagonal) from e regs
        float sd = 0.f;
        {
            float c;
            c = bf2f(f2bf(e0.x)); sd += c * c;  c = bf2f(f2bf(e0.y)); sd += c * c;
            c = bf2f(f2bf(e0.z)); sd += c * c;  c = bf2f(f2bf(e0.w)); sd += c * c;
            c = bf2f(f2bf(e1.x)); sd += c * c;  c = bf2f(f2bf(e1.y)); sd += c * c;
            c = bf2f(f2bf(e1.z)); sd += c * c;  c = bf2f(f2bf(e1.w)); sd += c * c;
            c = bf2f(f2bf(e2.x)); sd += c * c;  c = bf2f(f2bf(e2.y)); sd += c * c;
            c = bf2f(f2bf(e2.z)); sd += c * c;  c = bf2f(f2bf(e2.w)); sd += c * c;
            c = bf2f(f2bf(e3.x)); sd += c * c;  c = bf2f(f2bf(e3.y)); sd += c * c;
            c = bf2f(f2bf(e3.z)); sd += c * c;  c = bf2f(f2bf(e3.w)); sd += c * c;
        }
        sd += __shfl_xor(sd, 1, 64);
        sd += __shfl_xor(sd, 2, 64);
        sd += __shfl_xor(sd, 4, 64);
        sd += __shfl_xor(sd, 8, 64);

        if (lane == 0) {
            scr[r * 12 + w * 2]     = accs;
            scr[r * 12 + w * 2 + 1] = acce;
        }
        if (t == 0) scr[r * 12 + 8] = sd;
    }

    __syncthreads();
    if (t < NROWB * 12) sdpart[(size_t)b * (NROWB * 12) + t] = scr[t];

#undef STAGE_E
#undef STAGE_V
#undef COMP
}

// ---- kernel 3: per-row fold (32 gemm partials + 4 simdiv partials + self-term) ----
__global__ __launch_bounds__(128) void reduce1_kernel(
    const int* __restrict__ labels, const float* __restrict__ gden,
    const float* __restrict__ gnum, const float* __restrict__ sdpart,
    float* __restrict__ part)
{
    __shared__ float sA[128], sB[128];
    __shared__ int   sC[128];
    int p = blockIdx.x, t = threadIdx.x;
    int i = p * 128 + t;

    const float4* dr = reinterpret_cast<const float4*>(gden + (size_t)i * 32);
    const float4* nr = reinterpret_cast<const float4*>(gnum + (size_t)i * 32);
    const float* sp = sdpart + (size_t)(i >> 3) * (NROWB * 12) + (i & 7) * 12;

    float num = sp[0] + sp[2] + sp[4] + sp[6];
    float den = sp[1] + sp[3] + sp[5] + sp[7];
    float sdv = sp[8];
    int lab = labels[i];
    den -= __expf(sdv);           // remove j==i from denominator
    num -= lab ? sdv : 0.f;       // remove j==i from numerator if mal[i]

    #pragma unroll
    for (int c = 0; c < 8; ++c) {
        float4 a = dr[c]; den += a.x + a.y + a.z + a.w;
        float4 b = nr[c]; num += b.x + b.y + b.z + b.w;
    }
    sA[t] = lab ? __logf(den) : 0.f;
    sB[t] = lab ? num : 0.f;
    sC[t] = lab;
    __syncthreads();
    for (int s = 64; s > 0; s >>= 1) {
        if (t < s) { sA[t] += sA[t + s]; sB[t] += sB[t + s]; sC[t] += sC[t + s]; }
        __syncthreads();
    }
    if (t == 0) {
        part[p]      = sA[0];
        part[32 + p] = sB[0];
        part[64 + p] = (float)sC[0];
    }
}

// ---- kernel 4: final scalar combine ----
__global__ __launch_bounds__(64) void final_kernel(const float* __restrict__ part,
                                                   float* __restrict__ out)
{
    int lane = threadIdx.x;
    float lg = (lane < 32) ? part[lane]      : 0.f;
    float nm = (lane < 32) ? part[32 + lane] : 0.f;
    float ml = (lane < 32) ? part[64 + lane] : 0.f;
    #pragma unroll
    for (int s = 1; s < 64; s <<= 1) {
        lg += __shfl_xor(lg, s, 64);
        nm += __shfl_xor(nm, s, 64);
        ml += __shfl_xor(ml, s, 64);
    }
    if (lane == 0) {
        float cnt = ml - 1.f + (float)(SS + KKN);
        out[0] = (lg - nm / cnt) / (float)BTOT;
    }
}

extern "C" void kernel_launch(void* const* d_in, const int* in_sizes, int n_in,
                              void* d_out, int out_size, void* d_ws, size_t ws_size,
                              hipStream_t stream) {
    const float* E   = (const float*)d_in[0];
    const float* Sim = (const float*)d_in[1];
    const float* Div = (const float*)d_in[2];
    const int* labels = (const int*)d_in[3];
    float* out = (float*)d_out;

    char* ws = (char*)d_ws;
    u16*   ebf    = (u16*)ws;   ws += (size_t)BTOT * DD * sizeof(u16);
    float* gden   = (float*)ws; ws += (size_t)BTOT * 32 * sizeof(float);
    float* gnum   = (float*)ws; ws += (size_t)BTOT * 32 * sizeof(float);
    float* sdpart = (float*)ws; ws += (size_t)SDBLK * NROWB * 12 * sizeof(float);
    float* part   = (float*)ws;

    cast_kernel<<<BTOT * DD / 8 / 256, 256, 0, stream>>>(E, ebf);
    gemm_kernel<<<NGEMM, 256, 0, stream>>>(ebf, labels, gden, gnum);
    simdiv_kernel<<<SDBLK, 256, 65536 + 8192 + 384, stream>>>(E, Sim, Div, sdpart);
    reduce1_kernel<<<32, 128, 0, stream>>>(labels, gden, gnum, sdpart, part);
    final_kernel<<<1, 64, 0, stream>>>(part, out);
}

// Round 7
// 76.095 us; speedup vs baseline: 1.3797x; 1.0209x over previous
//
#include <hip/hip_runtime.h>
#include <stdint.h>

#define BTOT 4096
#define DD   256
#define SS   32
#define KKN  32
#define NGEMM 528          // 32*33/2 triangular tiles

typedef unsigned short u16;
using f32x4  = __attribute__((ext_vector_type(4))) float;
using bf16x8 = __attribute__((ext_vector_type(8))) short;

__device__ __forceinline__ u16 f2bf(float f) {
    uint32_t u = __builtin_bit_cast(uint32_t, f);
    u = (u + 0x7FFFu + ((u >> 16) & 1u)) >> 16;
    return (u16)u;
}
__device__ __forceinline__ float bf2f(u16 h) {
    uint32_t u = ((uint32_t)h) << 16;
    return __builtin_bit_cast(float, u);
}

// ---- kernel 0: cast embeddings fp32 -> bf16 ----
__global__ __launch_bounds__(256) void cast_kernel(const float* __restrict__ E,
                                                   u16* __restrict__ ebf) {
    int idx = blockIdx.x * 256 + threadIdx.x;
    const float4* p = reinterpret_cast<const float4*>(E) + (size_t)idx * 2;
    float4 a = p[0], b = p[1];
    uint4 o;
    o.x = (uint32_t)f2bf(a.x) | ((uint32_t)f2bf(a.y) << 16);
    o.y = (uint32_t)f2bf(a.z) | ((uint32_t)f2bf(a.w) << 16);
    o.z = (uint32_t)f2bf(b.x) | ((uint32_t)f2bf(b.y) << 16);
    o.w = (uint32_t)f2bf(b.z) | ((uint32_t)f2bf(b.w) << 16);
    reinterpret_cast<uint4*>(ebf)[idx] = o;
}

// ---- kernel 1: symmetric E@E^T, upper-triangular tiles (round-4, verified) ----
__global__ __launch_bounds__(256) void gemm_kernel(
    const u16* __restrict__ ebf, const int* __restrict__ labels,
    float* __restrict__ gden, float* __restrict__ gnum)
{
    __shared__ u16 As[128 * 32];
    __shared__ u16 Bs[128 * 32];
    __shared__ float rbuf[2][2][128];
    __shared__ float cbuf[2][2][128];

    int bid = blockIdx.x;
    int R = (int)((65.0f - sqrtf(4225.0f - 8.0f * (float)bid)) * 0.5f);
    while (R > 0 && R * (65 - R) / 2 > bid) --R;
    while ((R + 1) * (64 - R) / 2 <= bid) ++R;
    int C = R + (bid - R * (65 - R) / 2);

    int brow = R * 128, bcol = C * 128;
    int t = threadIdx.x, w = t >> 6, lane = t & 63;
    int wr = w >> 1, wc = w & 1;
    int r16 = lane & 15, hi = lane >> 4;
    int kq = hi * 8;

    f32x4 acc[4][4] = {};

    for (int kt = 0; kt < DD / 32; ++kt) {
        int k0 = kt * 32;
        #pragma unroll
        for (int it = 0; it < 2; ++it) {
            int c   = t + 256 * it;
            int row = c >> 2;
            int col = (c & 3) * 8;
            const u16* ga = &ebf[(size_t)(brow + row) * DD + k0 + col];
            const u16* gb = &ebf[(size_t)(bcol + row) * DD + k0 + col];
            __builtin_amdgcn_global_load_lds(
                (const __attribute__((address_space(1))) unsigned int*)ga,
                (__attribute__((address_space(3))) unsigned int*)&As[c * 8], 16, 0, 0);
            __builtin_amdgcn_global_load_lds(
                (const __attribute__((address_space(1))) unsigned int*)gb,
                (__attribute__((address_space(3))) unsigned int*)&Bs[c * 8], 16, 0, 0);
        }
        __syncthreads();

        bf16x8 af[4], bfr[4];
        #pragma unroll
        for (int m = 0; m < 4; ++m)
            af[m] = *(const bf16x8*)&As[(wr * 64 + m * 16 + r16) * 32 + kq];
        #pragma unroll
        for (int n = 0; n < 4; ++n)
            bfr[n] = *(const bf16x8*)&Bs[(wc * 64 + n * 16 + r16) * 32 + kq];
        #pragma unroll
        for (int m = 0; m < 4; ++m)
            #pragma unroll
            for (int n = 0; n < 4; ++n)
                acc[m][n] = __builtin_amdgcn_mfma_f32_16x16x32_bf16(af[m], bfr[n], acc[m][n], 0, 0, 0);
        __syncthreads();
    }

    bool offdiag = (C != R);

    float malf[4];
    #pragma unroll
    for (int n = 0; n < 4; ++n)
        malf[n] = (float)labels[bcol + wc * 64 + n * 16 + r16];
    float malr[16];
    #pragma unroll
    for (int m = 0; m < 4; ++m)
        #pragma unroll
        for (int r = 0; r < 4; ++r)
            malr[m * 4 + r] = (float)labels[brow + wr * 64 + m * 16 + hi * 4 + r];

    float cd[4] = {0.f, 0.f, 0.f, 0.f}, cn[4] = {0.f, 0.f, 0.f, 0.f};

    #pragma unroll
    for (int m = 0; m < 4; ++m) {
        #pragma unroll
        for (int r = 0; r < 4; ++r) {
            float pe = 0.f, pn = 0.f;
            #pragma unroll
            for (int n = 0; n < 4; ++n) {
                float v  = acc[m][n][r];
                float ex = __expf(v);
                pe += ex;
                pn += malf[n] * v;
                cd[n] += ex;
                cn[n] += malr[m * 4 + r] * v;
            }
            #pragma unroll
            for (int s = 1; s < 16; s <<= 1) {
                pe += __shfl_xor(pe, s, 64);
                pn += __shfl_xor(pn, s, 64);
            }
            if (r16 == 0) {
                int rl = wr * 64 + m * 16 + hi * 4 + r;
                rbuf[0][wc][rl] = pe;
                rbuf[1][wc][rl] = pn;
            }
        }
    }

    if (offdiag) {
        #pragma unroll
        for (int n = 0; n < 4; ++n) {
            cd[n] += __shfl_xor(cd[n], 16, 64);
            cd[n] += __shfl_xor(cd[n], 32, 64);
            cn[n] += __shfl_xor(cn[n], 16, 64);
            cn[n] += __shfl_xor(cn[n], 32, 64);
            if (lane < 16) {
                int cl = wc * 64 + n * 16 + lane;
                cbuf[0][wr][cl] = cd[n];
                cbuf[1][wr][cl] = cn[n];
            }
        }
    }
    __syncthreads();

    if (t < 128) {
        int i = brow + t;
        gden[(size_t)i * 32 + C] = rbuf[0][0][t] + rbuf[0][1][t];
        gnum[(size_t)i * 32 + C] = rbuf[1][0][t] + rbuf[1][1][t];
    } else if (offdiag) {
        int tt = t - 128;
        int j = bcol + tt;
        gden[(size_t)j * 32 + R] = cbuf[0][0][tt] + cbuf[0][1][tt];
        gnum[(size_t)j * 32 + R] = cbuf[1][0][tt] + cbuf[1][1][tt];
    }
}

// ---- kernel 2: simdiv, register-direct (no LDS, no barriers, no atomics) ----
// One wave per row. Group g (16 lanes) owns vector set*4+g; lane reads 16B
// at chunk c. 16 sets, 4-set register double-buffer = 16 loads (16KB) in
// flight per wave; 16 waves/CU (VGPR<=128). Dot = 16 FMA + 4-shuffle group
// reduce + exp. Per-row partials stored directly by lane 0.
__global__ __launch_bounds__(256, 4) void simdiv_kernel(
    const float* __restrict__ E, const float* __restrict__ Sim, const float* __restrict__ Div,
    float* __restrict__ sdpart)
{
    int i    = blockIdx.x * 4 + (threadIdx.x >> 6);   // one row per wave
    int lane = threadIdx.x & 63;
    int g = lane >> 4, sub = lane & 15;

    const char* Eb = (const char*)(E + (size_t)i * DD);
    float4 e0 = *(const float4*)(Eb + 0 * 256 + sub * 16);
    float4 e1 = *(const float4*)(Eb + 1 * 256 + sub * 16);
    float4 e2 = *(const float4*)(Eb + 2 * 256 + sub * 16);
    float4 e3 = *(const float4*)(Eb + 3 * 256 + sub * 16);

    const char* Sb = (const char*)(Sim + (size_t)i * SS * DD) + g * 1024 + sub * 16;
    const char* Db = (const char*)(Div + (size_t)i * KKN * DD) + g * 1024 + sub * 16;

    float4 buf[4][4];
    float accs = 0.f, acce = 0.f;

#define ISSUE(SET)                                                                  \
    {                                                                               \
        const char* b_ = ((SET) < 8) ? (Sb + (SET) * 4096) : (Db + ((SET) - 8) * 4096); \
        buf[(SET) & 3][0] = *(const float4*)(b_ + 0);                               \
        buf[(SET) & 3][1] = *(const float4*)(b_ + 256);                             \
        buf[(SET) & 3][2] = *(const float4*)(b_ + 512);                             \
        buf[(SET) & 3][3] = *(const float4*)(b_ + 768);                             \
    }

#define COMPUTE(SET)                                                                \
    {                                                                               \
        float4 s0 = buf[(SET) & 3][0], s1 = buf[(SET) & 3][1];                      \
        float4 s2 = buf[(SET) & 3][2], s3 = buf[(SET) & 3][3];                      \
        float d = e0.x * s0.x + e0.y * s0.y + e0.z * s0.z + e0.w * s0.w             \
                + e1.x * s1.x + e1.y * s1.y + e1.z * s1.z + e1.w * s1.w             \
                + e2.x * s2.x + e2.y * s2.y + e2.z * s2.z + e2.w * s2.w             \
                + e3.x * s3.x + e3.y * s3.y + e3.z * s3.z + e3.w * s3.w;            \
        d += __shfl_xor(d, 1, 64);                                                  \
        d += __shfl_xor(d, 2, 64);                                                  \
        d += __shfl_xor(d, 4, 64);                                                  \
        d += __shfl_xor(d, 8, 64);                                                  \
        accs += d;                                                                  \
        acce += __expf(d);                                                          \
    }

    ISSUE(0) ISSUE(1) ISSUE(2) ISSUE(3)
    COMPUTE(0)  ISSUE(4)
    COMPUTE(1)  ISSUE(5)
    COMPUTE(2)  ISSUE(6)
    COMPUTE(3)  ISSUE(7)
    COMPUTE(4)  ISSUE(8)
    COMPUTE(5)  ISSUE(9)
    COMPUTE(6)  ISSUE(10)
    COMPUTE(7)  ISSUE(11)
    COMPUTE(8)  ISSUE(12)
    COMPUTE(9)  ISSUE(13)
    COMPUTE(10) ISSUE(14)
    COMPUTE(11) ISSUE(15)
    COMPUTE(12)
    COMPUTE(13)
    COMPUTE(14)
    COMPUTE(15)
#undef ISSUE
#undef COMPUTE

    // cross-group reduce
    accs += __shfl_xor(accs, 16, 64);
    accs += __shfl_xor(accs, 32, 64);
    acce += __shfl_xor(acce, 16, 64);
    acce += __shfl_xor(acce, 32, 64);

    // self-dot (bf16-rounded, matches MFMA diagonal); e chunks cover all 256
    float sd = 0.f;
    {
        float c;
        c = bf2f(f2bf(e0.x)); sd += c * c;  c = bf2f(f2bf(e0.y)); sd += c * c;
        c = bf2f(f2bf(e0.z)); sd += c * c;  c = bf2f(f2bf(e0.w)); sd += c * c;
        c = bf2f(f2bf(e1.x)); sd += c * c;  c = bf2f(f2bf(e1.y)); sd += c * c;
        c = bf2f(f2bf(e1.z)); sd += c * c;  c = bf2f(f2bf(e1.w)); sd += c * c;
        c = bf2f(f2bf(e2.x)); sd += c * c;  c = bf2f(f2bf(e2.y)); sd += c * c;
        c = bf2f(f2bf(e2.z)); sd += c * c;  c = bf2f(f2bf(e2.w)); sd += c * c;
        c = bf2f(f2bf(e3.x)); sd += c * c;  c = bf2f(f2bf(e3.y)); sd += c * c;
        c = bf2f(f2bf(e3.z)); sd += c * c;  c = bf2f(f2bf(e3.w)); sd += c * c;
    }
    sd += __shfl_xor(sd, 1, 64);
    sd += __shfl_xor(sd, 2, 64);
    sd += __shfl_xor(sd, 4, 64);
    sd += __shfl_xor(sd, 8, 64);

    if (lane == 0) {
        float4 o; o.x = accs; o.y = acce; o.z = sd; o.w = 0.f;
        *(float4*)(sdpart + (size_t)i * 4) = o;
    }
}

// ---- kernel 3: per-row fold (32 gemm partials + simdiv partials + self-term) ----
__global__ __launch_bounds__(128) void reduce1_kernel(
    const int* __restrict__ labels, const float* __restrict__ gden,
    const float* __restrict__ gnum, const float* __restrict__ sdpart,
    float* __restrict__ part)
{
    __shared__ float sA[128], sB[128];
    __shared__ int   sC[128];
    int p = blockIdx.x, t = threadIdx.x;
    int i = p * 128 + t;

    const float4* dr = reinterpret_cast<const float4*>(gden + (size_t)i * 32);
    const float4* nr = reinterpret_cast<const float4*>(gnum + (size_t)i * 32);
    float4 sp = *(const float4*)(sdpart + (size_t)i * 4);

    float num = sp.x;
    float den = sp.y;
    float sdv = sp.z;
    int lab = labels[i];
    den -= __expf(sdv);           // remove j==i from denominator
    num -= lab ? sdv : 0.f;       // remove j==i from numerator if mal[i]

    #pragma unroll
    for (int c = 0; c < 8; ++c) {
        float4 a = dr[c]; den += a.x + a.y + a.z + a.w;
        float4 b = nr[c]; num += b.x + b.y + b.z + b.w;
    }
    sA[t] = lab ? __logf(den) : 0.f;
    sB[t] = lab ? num : 0.f;
    sC[t] = lab;
    __syncthreads();
    for (int s = 64; s > 0; s >>= 1) {
        if (t < s) { sA[t] += sA[t + s]; sB[t] += sB[t + s]; sC[t] += sC[t + s]; }
        __syncthreads();
    }
    if (t == 0) {
        part[p]      = sA[0];
        part[32 + p] = sB[0];
        part[64 + p] = (float)sC[0];
    }
}

// ---- kernel 4: final scalar combine ----
__global__ __launch_bounds__(64) void final_kernel(const float* __restrict__ part,
                                                   float* __restrict__ out)
{
    int lane = threadIdx.x;
    float lg = (lane < 32) ? part[lane]      : 0.f;
    float nm = (lane < 32) ? part[32 + lane] : 0.f;
    float ml = (lane < 32) ? part[64 + lane] : 0.f;
    #pragma unroll
    for (int s = 1; s < 64; s <<= 1) {
        lg += __shfl_xor(lg, s, 64);
        nm += __shfl_xor(nm, s, 64);
        ml += __shfl_xor(ml, s, 64);
    }
    if (lane == 0) {
        float cnt = ml - 1.f + (float)(SS + KKN);
        out[0] = (lg - nm / cnt) / (float)BTOT;
    }
}

extern "C" void kernel_launch(void* const* d_in, const int* in_sizes, int n_in,
                              void* d_out, int out_size, void* d_ws, size_t ws_size,
                              hipStream_t stream) {
    const float* E   = (const float*)d_in[0];
    const float* Sim = (const float*)d_in[1];
    const float* Div = (const float*)d_in[2];
    const int* labels = (const int*)d_in[3];
    float* out = (float*)d_out;

    char* ws = (char*)d_ws;
    u16*   ebf    = (u16*)ws;   ws += (size_t)BTOT * DD * sizeof(u16);
    float* gden   = (float*)ws; ws += (size_t)BTOT * 32 * sizeof(float);
    float* gnum   = (float*)ws; ws += (size_t)BTOT * 32 * sizeof(float);
    float* sdpart = (float*)ws; ws += (size_t)BTOT * 4 * sizeof(float);
    float* part   = (float*)ws;

    cast_kernel<<<BTOT * DD / 8 / 256, 256, 0, stream>>>(E, ebf);
    gemm_kernel<<<NGEMM, 256, 0, stream>>>(ebf, labels, gden, gnum);
    simdiv_kernel<<<BTOT / 4, 256, 0, stream>>>(E, Sim, Div, sdpart);
    reduce1_kernel<<<32, 128, 0, stream>>>(labels, gden, gnum, sdpart, part);
    final_kernel<<<1, 64, 0, stream>>>(part, out);
}

// Round 8
// 65.701 us; speedup vs baseline: 1.5980x; 1.1582x over previous
//
#include <hip/hip_runtime.h>
#include <stdint.h>

#define BTOT 4096
#define DD   256
#define SS   32
#define KKN  32
#define NGEMM 528              // 32*33/2 triangular tiles
#define NBLK  (NGEMM * 3)      // 1584: 1-in-3 gemm, rest simdiv (1056, 1024 used)

typedef unsigned short u16;
using f32x4  = __attribute__((ext_vector_type(4))) float;
using bf16x8 = __attribute__((ext_vector_type(8))) short;

__device__ __forceinline__ u16 f2bf(float f) {
    uint32_t u = __builtin_bit_cast(uint32_t, f);
    u = (u + 0x7FFFu + ((u >> 16) & 1u)) >> 16;
    return (u16)u;
}
__device__ __forceinline__ float bf2f(u16 h) {
    uint32_t u = ((uint32_t)h) << 16;
    return __builtin_bit_cast(float, u);
}

// ---- kernel 0: cast embeddings fp32 -> bf16 ----
__global__ __launch_bounds__(256) void cast_kernel(const float* __restrict__ E,
                                                   u16* __restrict__ ebf) {
    int idx = blockIdx.x * 256 + threadIdx.x;
    const float4* p = reinterpret_cast<const float4*>(E) + (size_t)idx * 2;
    float4 a = p[0], b = p[1];
    uint4 o;
    o.x = (uint32_t)f2bf(a.x) | ((uint32_t)f2bf(a.y) << 16);
    o.y = (uint32_t)f2bf(a.z) | ((uint32_t)f2bf(a.w) << 16);
    o.z = (uint32_t)f2bf(b.x) | ((uint32_t)f2bf(b.y) << 16);
    o.w = (uint32_t)f2bf(b.z) | ((uint32_t)f2bf(b.w) << 16);
    reinterpret_cast<uint4*>(ebf)[idx] = o;
}

// ---- fat kernel: bid%3==2 -> triangular GEMM tile; else -> simdiv rows ----
// simdiv path is LDS-free/register-direct, so gemm's 20KB static LDS no
// longer caps simdiv co-residency (round-5 failure mechanism removed).
__global__ __launch_bounds__(256) void fat_kernel(
    const float* __restrict__ E, const float* __restrict__ Sim, const float* __restrict__ Div,
    const u16* __restrict__ ebf, const int* __restrict__ labels,
    float* __restrict__ gden, float* __restrict__ gnum, float* __restrict__ sdpart)
{
    __shared__ u16 As[128 * 32];
    __shared__ u16 Bs[128 * 32];
    __shared__ float rbuf[2][2][128];
    __shared__ float cbuf[2][2][128];

    int bid  = blockIdx.x;
    int t    = threadIdx.x;
    int w    = t >> 6;
    int lane = t & 63;

    if (bid % 3 == 2) {
        // ================= GEMM path (round-4 verified body) =================
        int g = bid / 3;
        int R = (int)((65.0f - sqrtf(4225.0f - 8.0f * (float)g)) * 0.5f);
        while (R > 0 && R * (65 - R) / 2 > g) --R;
        while ((R + 1) * (64 - R) / 2 <= g) ++R;
        int C = R + (g - R * (65 - R) / 2);

        int brow = R * 128, bcol = C * 128;
        int wr = w >> 1, wc = w & 1;
        int r16 = lane & 15, hi = lane >> 4;
        int kq = hi * 8;

        f32x4 acc[4][4] = {};

        for (int kt = 0; kt < DD / 32; ++kt) {
            int k0 = kt * 32;
            #pragma unroll
            for (int it = 0; it < 2; ++it) {
                int c   = t + 256 * it;
                int row = c >> 2;
                int col = (c & 3) * 8;
                const u16* ga = &ebf[(size_t)(brow + row) * DD + k0 + col];
                const u16* gb = &ebf[(size_t)(bcol + row) * DD + k0 + col];
                __builtin_amdgcn_global_load_lds(
                    (const __attribute__((address_space(1))) unsigned int*)ga,
                    (__attribute__((address_space(3))) unsigned int*)&As[c * 8], 16, 0, 0);
                __builtin_amdgcn_global_load_lds(
                    (const __attribute__((address_space(1))) unsigned int*)gb,
                    (__attribute__((address_space(3))) unsigned int*)&Bs[c * 8], 16, 0, 0);
            }
            __syncthreads();

            bf16x8 af[4], bfr[4];
            #pragma unroll
            for (int m = 0; m < 4; ++m)
                af[m] = *(const bf16x8*)&As[(wr * 64 + m * 16 + r16) * 32 + kq];
            #pragma unroll
            for (int n = 0; n < 4; ++n)
                bfr[n] = *(const bf16x8*)&Bs[(wc * 64 + n * 16 + r16) * 32 + kq];
            #pragma unroll
            for (int m = 0; m < 4; ++m)
                #pragma unroll
                for (int n = 0; n < 4; ++n)
                    acc[m][n] = __builtin_amdgcn_mfma_f32_16x16x32_bf16(af[m], bfr[n], acc[m][n], 0, 0, 0);
            __syncthreads();
        }

        bool offdiag = (C != R);

        float malf[4];
        #pragma unroll
        for (int n = 0; n < 4; ++n)
            malf[n] = (float)labels[bcol + wc * 64 + n * 16 + r16];
        float malr[16];
        #pragma unroll
        for (int m = 0; m < 4; ++m)
            #pragma unroll
            for (int r = 0; r < 4; ++r)
                malr[m * 4 + r] = (float)labels[brow + wr * 64 + m * 16 + hi * 4 + r];

        float cd[4] = {0.f, 0.f, 0.f, 0.f}, cn[4] = {0.f, 0.f, 0.f, 0.f};

        #pragma unroll
        for (int m = 0; m < 4; ++m) {
            #pragma unroll
            for (int r = 0; r < 4; ++r) {
                float pe = 0.f, pn = 0.f;
                #pragma unroll
                for (int n = 0; n < 4; ++n) {
                    float v  = acc[m][n][r];
                    float ex = __expf(v);
                    pe += ex;
                    pn += malf[n] * v;
                    cd[n] += ex;
                    cn[n] += malr[m * 4 + r] * v;
                }
                #pragma unroll
                for (int s = 1; s < 16; s <<= 1) {
                    pe += __shfl_xor(pe, s, 64);
                    pn += __shfl_xor(pn, s, 64);
                }
                if (r16 == 0) {
                    int rl = wr * 64 + m * 16 + hi * 4 + r;
                    rbuf[0][wc][rl] = pe;
                    rbuf[1][wc][rl] = pn;
                }
            }
        }

        if (offdiag) {
            #pragma unroll
            for (int n = 0; n < 4; ++n) {
                cd[n] += __shfl_xor(cd[n], 16, 64);
                cd[n] += __shfl_xor(cd[n], 32, 64);
                cn[n] += __shfl_xor(cn[n], 16, 64);
                cn[n] += __shfl_xor(cn[n], 32, 64);
                if (lane < 16) {
                    int cl = wc * 64 + n * 16 + lane;
                    cbuf[0][wr][cl] = cd[n];
                    cbuf[1][wr][cl] = cn[n];
                }
            }
        }
        __syncthreads();

        if (t < 128) {
            int i = brow + t;
            gden[(size_t)i * 32 + C] = rbuf[0][0][t] + rbuf[0][1][t];
            gnum[(size_t)i * 32 + C] = rbuf[1][0][t] + rbuf[1][1][t];
        } else if (offdiag) {
            int tt = t - 128;
            int j = bcol + tt;
            gden[(size_t)j * 32 + R] = cbuf[0][0][tt] + cbuf[0][1][tt];
            gnum[(size_t)j * 32 + R] = cbuf[1][0][tt] + cbuf[1][1][tt];
        }
    } else {
        // ================= simdiv path (round-7 register-direct) =================
        int sid = bid - bid / 3;            // 0..1055 over non-gemm bids
        if (sid >= BTOT / 4) return;
        int i = sid * 4 + w;                // one wave per row
        int g = lane >> 4, sub = lane & 15;

        const char* Eb = (const char*)(E + (size_t)i * DD);
        float4 e0 = *(const float4*)(Eb + 0 * 256 + sub * 16);
        float4 e1 = *(const float4*)(Eb + 1 * 256 + sub * 16);
        float4 e2 = *(const float4*)(Eb + 2 * 256 + sub * 16);
        float4 e3 = *(const float4*)(Eb + 3 * 256 + sub * 16);

        const char* Sb = (const char*)(Sim + (size_t)i * SS * DD) + g * 1024 + sub * 16;
        const char* Db = (const char*)(Div + (size_t)i * KKN * DD) + g * 1024 + sub * 16;

        float4 buf[4][4];
        float accs = 0.f, acce = 0.f;

#define ISSUE(SET)                                                                  \
    {                                                                               \
        const char* b_ = ((SET) < 8) ? (Sb + (SET) * 4096) : (Db + ((SET) - 8) * 4096); \
        buf[(SET) & 3][0] = *(const float4*)(b_ + 0);                               \
        buf[(SET) & 3][1] = *(const float4*)(b_ + 256);                             \
        buf[(SET) & 3][2] = *(const float4*)(b_ + 512);                             \
        buf[(SET) & 3][3] = *(const float4*)(b_ + 768);                             \
    }

#define COMPUTE(SET)                                                                \
    {                                                                               \
        float4 s0 = buf[(SET) & 3][0], s1 = buf[(SET) & 3][1];                      \
        float4 s2 = buf[(SET) & 3][2], s3 = buf[(SET) & 3][3];                      \
        float d = e0.x * s0.x + e0.y * s0.y + e0.z * s0.z + e0.w * s0.w             \
                + e1.x * s1.x + e1.y * s1.y + e1.z * s1.z + e1.w * s1.w             \
                + e2.x * s2.x + e2.y * s2.y + e2.z * s2.z + e2.w * s2.w             \
                + e3.x * s3.x + e3.y * s3.y + e3.z * s3.z + e3.w * s3.w;            \
        d += __shfl_xor(d, 1, 64);                                                  \
        d += __shfl_xor(d, 2, 64);                                                  \
        d += __shfl_xor(d, 4, 64);                                                  \
        d += __shfl_xor(d, 8, 64);                                                  \
        accs += d;                                                                  \
        acce += __expf(d);                                                          \
    }

        ISSUE(0) ISSUE(1) ISSUE(2) ISSUE(3)
        COMPUTE(0)  ISSUE(4)
        COMPUTE(1)  ISSUE(5)
        COMPUTE(2)  ISSUE(6)
        COMPUTE(3)  ISSUE(7)
        COMPUTE(4)  ISSUE(8)
        COMPUTE(5)  ISSUE(9)
        COMPUTE(6)  ISSUE(10)
        COMPUTE(7)  ISSUE(11)
        COMPUTE(8)  ISSUE(12)
        COMPUTE(9)  ISSUE(13)
        COMPUTE(10) ISSUE(14)
        COMPUTE(11) ISSUE(15)
        COMPUTE(12)
        COMPUTE(13)
        COMPUTE(14)
        COMPUTE(15)
#undef ISSUE
#undef COMPUTE

        accs += __shfl_xor(accs, 16, 64);
        accs += __shfl_xor(accs, 32, 64);
        acce += __shfl_xor(acce, 16, 64);
        acce += __shfl_xor(acce, 32, 64);

        // self-dot (bf16-rounded, matches MFMA diagonal)
        float sd = 0.f;
        {
            float c;
            c = bf2f(f2bf(e0.x)); sd += c * c;  c = bf2f(f2bf(e0.y)); sd += c * c;
            c = bf2f(f2bf(e0.z)); sd += c * c;  c = bf2f(f2bf(e0.w)); sd += c * c;
            c = bf2f(f2bf(e1.x)); sd += c * c;  c = bf2f(f2bf(e1.y)); sd += c * c;
            c = bf2f(f2bf(e1.z)); sd += c * c;  c = bf2f(f2bf(e1.w)); sd += c * c;
            c = bf2f(f2bf(e2.x)); sd += c * c;  c = bf2f(f2bf(e2.y)); sd += c * c;
            c = bf2f(f2bf(e2.z)); sd += c * c;  c = bf2f(f2bf(e2.w)); sd += c * c;
            c = bf2f(f2bf(e3.x)); sd += c * c;  c = bf2f(f2bf(e3.y)); sd += c * c;
            c = bf2f(f2bf(e3.z)); sd += c * c;  c = bf2f(f2bf(e3.w)); sd += c * c;
        }
        sd += __shfl_xor(sd, 1, 64);
        sd += __shfl_xor(sd, 2, 64);
        sd += __shfl_xor(sd, 4, 64);
        sd += __shfl_xor(sd, 8, 64);

        if (lane == 0) {
            float4 o; o.x = accs; o.y = acce; o.z = sd; o.w = 0.f;
            *(float4*)(sdpart + (size_t)i * 4) = o;
        }
    }
}

// ---- kernel 3: per-row fold (32 gemm partials + simdiv partials + self-term) ----
__global__ __launch_bounds__(128) void reduce1_kernel(
    const int* __restrict__ labels, const float* __restrict__ gden,
    const float* __restrict__ gnum, const float* __restrict__ sdpart,
    float* __restrict__ part)
{
    __shared__ float sA[128], sB[128];
    __shared__ int   sC[128];
    int p = blockIdx.x, t = threadIdx.x;
    int i = p * 128 + t;

    const float4* dr = reinterpret_cast<const float4*>(gden + (size_t)i * 32);
    const float4* nr = reinterpret_cast<const float4*>(gnum + (size_t)i * 32);
    float4 sp = *(const float4*)(sdpart + (size_t)i * 4);

    float num = sp.x;
    float den = sp.y;
    float sdv = sp.z;
    int lab = labels[i];
    den -= __expf(sdv);           // remove j==i from denominator
    num -= lab ? sdv : 0.f;       // remove j==i from numerator if mal[i]

    #pragma unroll
    for (int c = 0; c < 8; ++c) {
        float4 a = dr[c]; den += a.x + a.y + a.z + a.w;
        float4 b = nr[c]; num += b.x + b.y + b.z + b.w;
    }
    sA[t] = lab ? __logf(den) : 0.f;
    sB[t] = lab ? num : 0.f;
    sC[t] = lab;
    __syncthreads();
    for (int s = 64; s > 0; s >>= 1) {
        if (t < s) { sA[t] += sA[t + s]; sB[t] += sB[t + s]; sC[t] += sC[t + s]; }
        __syncthreads();
    }
    if (t == 0) {
        part[p]      = sA[0];
        part[32 + p] = sB[0];
        part[64 + p] = (float)sC[0];
    }
}

// ---- kernel 4: final scalar combine ----
__global__ __launch_bounds__(64) void final_kernel(const float* __restrict__ part,
                                                   float* __restrict__ out)
{
    int lane = threadIdx.x;
    float lg = (lane < 32) ? part[lane]      : 0.f;
    float nm = (lane < 32) ? part[32 + lane] : 0.f;
    float ml = (lane < 32) ? part[64 + lane] : 0.f;
    #pragma unroll
    for (int s = 1; s < 64; s <<= 1) {
        lg += __shfl_xor(lg, s, 64);
        nm += __shfl_xor(nm, s, 64);
        ml += __shfl_xor(ml, s, 64);
    }
    if (lane == 0) {
        float cnt = ml - 1.f + (float)(SS + KKN);
        out[0] = (lg - nm / cnt) / (float)BTOT;
    }
}

extern "C" void kernel_launch(void* const* d_in, const int* in_sizes, int n_in,
                              void* d_out, int out_size, void* d_ws, size_t ws_size,
                              hipStream_t stream) {
    const float* E   = (const float*)d_in[0];
    const float* Sim = (const float*)d_in[1];
    const float* Div = (const float*)d_in[2];
    const int* labels = (const int*)d_in[3];
    float* out = (float*)d_out;

    char* ws = (char*)d_ws;
    u16*   ebf    = (u16*)ws;   ws += (size_t)BTOT * DD * sizeof(u16);
    float* gden   = (float*)ws; ws += (size_t)BTOT * 32 * sizeof(float);
    float* gnum   = (float*)ws; ws += (size_t)BTOT * 32 * sizeof(float);
    float* sdpart = (float*)ws; ws += (size_t)BTOT * 4 * sizeof(float);
    float* part   = (float*)ws;

    cast_kernel<<<BTOT * DD / 8 / 256, 256, 0, stream>>>(E, ebf);
    fat_kernel<<<NBLK, 256, 0, stream>>>(E, Sim, Div, ebf, labels, gden, gnum, sdpart);
    reduce1_kernel<<<32, 128, 0, stream>>>(labels, gden, gnum, sdpart, part);
    final_kernel<<<1, 64, 0, stream>>>(part, out);
}